// Round 2
// baseline (122.306 us; speedup 1.0000x reference)
//
#include <hip/hip_runtime.h>
#include <math.h>

#define Bn 4
#define Hn 512
#define Wn 229
#define Cn 32
#define OUTn 88
#define BH (Bn*Hn)            // 2048
#define NPOS (BH*Wn)          // 468992 = 1832 * 256 exactly
#define FP_SIZE (BH*OUTn)     // 180224
#define CW (Cn*Wn)            // 7328

// workspace layout (float offsets)
#define WS_WEFF 16            // Wn*OUTn = 20152 floats, layout [w][o] (s_load-friendly in head)
#define WS_O    (16 + Wn*OUTn) // Wn*BH floats, layout [w][bh]

// ---------------- kernel 1: effective head matrix ----------------
// Weff[w][o] = sum_c W_lin[o*CW + c*Wn + w] * Wv[c]
// mapping o=tid/229, w=tid%229 -> consecutive lanes share o, consecutive w
// -> W_lin reads coalesced (229-float contiguous runs per (o,c)).
__global__ __launch_bounds__(256) void prep_kernel(
    const float* __restrict__ Wv, const float* __restrict__ W_lin,
    float* __restrict__ ws) {
  __shared__ float wv[Cn];
  if (threadIdx.x < Cn) wv[threadIdx.x] = Wv[threadIdx.x];
  __syncthreads();
  const int tid = blockIdx.x * 256 + threadIdx.x;
  if (tid >= Wn * OUTn) return;
  const int o = tid / Wn;
  const int w = tid - o * Wn;
  const float* src = W_lin + o * CW + w;
  float acc = 0.f;
  #pragma unroll
  for (int c = 0; c < Cn; ++c) acc += src[c * Wn] * wv[c];
  ws[WS_WEFF + w * OUTn + o] = acc;   // scattered (stride 352B) but only 80 KB, L2-merged
}

// ---------------- kernel 2: per-position attention ----------------
__global__ __launch_bounds__(256) void attn_kernel(
    const float* __restrict__ spec,
    const float* __restrict__ Wq, const float* __restrict__ Wk,
    const float* __restrict__ rel_t, const float* __restrict__ rel_f,
    float* __restrict__ out, float* __restrict__ o_ws) {
  __shared__ float scal[8];
  __shared__ __align__(16) float satt[256 * 9];

  // lanes 0..6 compute the 7 collapsed scalars: A, Rt[0..2], Rf[0..2]
  if (threadIdx.x < 7) {
    const int t = threadIdx.x;
    float acc = 0.f;
    if (t == 0) {
      #pragma unroll
      for (int c = 0; c < Cn; ++c) acc += Wq[c] * Wk[c];
    } else if (t < 4) {
      const int i = t - 1;
      #pragma unroll
      for (int c = 0; c < 16; ++c) acc += Wq[c] * rel_t[c*3 + i];
    } else {
      const int j = t - 4;
      #pragma unroll
      for (int c = 0; c < 16; ++c) acc += Wq[16 + c] * rel_f[c*3 + j];
    }
    scal[t] = acc;
  }
  __syncthreads();

  const int idx = blockIdx.x * 256 + threadIdx.x;   // = bh*Wn + w
  const int bh  = idx / Wn;
  const int w   = idx - bh * Wn;
  const int h   = bh & (Hn - 1);

  const float A = scal[0];
  const float s = spec[idx];

  float e[9], sp[9];
  float m = -1e30f;
  #pragma unroll
  for (int i = 0; i < 3; ++i) {
    const int hh = h + i - 1;
    const bool hin = (unsigned)hh < (unsigned)Hn;
    const float rt = scal[1 + i];
    #pragma unroll
    for (int j = 0; j < 3; ++j) {
      const int ww = w + j - 1;
      const bool in = hin && ((unsigned)ww < (unsigned)Wn);
      const int k = i*3 + j;
      const float v = in ? spec[idx + (i-1)*Wn + (j-1)] : 0.f;
      sp[k] = v;
      const float ek = s * (fmaf(A, v, rt) + scal[4 + j]);
      e[k] = ek;
      m = fmaxf(m, ek);
    }
  }
  float sum = 0.f;
  #pragma unroll
  for (int k = 0; k < 9; ++k) { e[k] = __expf(e[k] - m); sum += e[k]; }
  const float inv = 1.f / sum;
  float o = 0.f;
  #pragma unroll
  for (int k = 0; k < 9; ++k) {
    const float a = e[k] * inv;
    satt[threadIdx.x * 9 + k] = a;
    o = fmaf(a, sp[k], o);
  }
  o_ws[w * BH + bh] = o;   // transposed store for head kernel (L2-merged)

  __syncthreads();
  // 2304 floats = 576 float4, coalesced vector copy LDS -> global
  float4* dst4 = (float4*)(out + FP_SIZE + (size_t)blockIdx.x * 2304);
  const float4* s4 = (const float4*)satt;
  #pragma unroll
  for (int r = 0; r < 2; ++r) {
    const int p = r * 256 + threadIdx.x;
    dst4[p] = s4[p];
  }
  {
    const int p = 512 + threadIdx.x;
    if (p < 576) dst4[p] = s4[p];
  }
}

// ---------------- kernel 3: frame head ----------------
// grid = 16 bh-chunks * 11 o-groups = 176 blocks of 128 threads
__global__ __launch_bounds__(128) void head_kernel(
    const float* __restrict__ ws, const float* __restrict__ b_lin,
    float* __restrict__ out) {
  const int og = blockIdx.x % 11;
  const int bh = (blockIdx.x / 11) * 128 + threadIdx.x;
  const float* WeffT = ws + WS_WEFF;
  const float* ovec  = ws + WS_O;

  float acc[8];
  #pragma unroll
  for (int u = 0; u < 8; ++u) acc[u] = b_lin[og*8 + u];

  #pragma unroll 4
  for (int w = 0; w < Wn; ++w) {
    const float x = ovec[w * BH + bh];            // coalesced, L2-hot
    const float* wr = WeffT + w * OUTn + og * 8;  // wave-uniform -> s_load
    #pragma unroll
    for (int u = 0; u < 8; ++u) acc[u] = fmaf(wr[u], x, acc[u]);
  }

  float4 r0, r1;
  r0.x = 1.f/(1.f+__expf(-acc[0])); r0.y = 1.f/(1.f+__expf(-acc[1]));
  r0.z = 1.f/(1.f+__expf(-acc[2])); r0.w = 1.f/(1.f+__expf(-acc[3]));
  r1.x = 1.f/(1.f+__expf(-acc[4])); r1.y = 1.f/(1.f+__expf(-acc[5]));
  r1.z = 1.f/(1.f+__expf(-acc[6])); r1.w = 1.f/(1.f+__expf(-acc[7]));
  float4* d = (float4*)(out + (size_t)bh * OUTn + og * 8);  // 16B aligned: 88*4 and 8*4 both /16... (352,32)
  d[0] = r0; d[1] = r1;
}

extern "C" void kernel_launch(void* const* d_in, const int* in_sizes, int n_in,
                              void* d_out, int out_size, void* d_ws, size_t ws_size,
                              hipStream_t stream) {
  const float* spec  = (const float*)d_in[0];
  const float* Wq    = (const float*)d_in[1];
  const float* Wk    = (const float*)d_in[2];
  const float* Wv    = (const float*)d_in[3];
  const float* rel_t = (const float*)d_in[4];
  const float* rel_f = (const float*)d_in[5];
  const float* W_lin = (const float*)d_in[6];
  const float* b_lin = (const float*)d_in[7];
  float* out = (float*)d_out;
  float* ws  = (float*)d_ws;

  attn_kernel<<<NPOS/256, 256, 0, stream>>>(spec, Wq, Wk, rel_t, rel_f, out, ws + WS_O);
  prep_kernel<<<(Wn*OUTn + 255)/256, 256, 0, stream>>>(Wv, W_lin, ws);
  head_kernel<<<176, 128, 0, stream>>>(ws, b_lin, out);
}

// Round 3
// 98.678 us; speedup vs baseline: 1.2395x; 1.2395x over previous
//
#include <hip/hip_runtime.h>
#include <math.h>

#define Bn 4
#define Hn 512
#define Wn 229
#define Cn 32
#define OUTn 88
#define BH (Bn*Hn)            // 2048
#define FP_SIZE (BH*OUTn)     // 180224
#define CW (Cn*Wn)            // 7328
#define KK 9                  // 3x3 window
#define ATT_ROW (Wn*KK)       // 2061 floats per bh row

// workspace layout (float offsets)
#define WS_SCAL 0             // 8 floats: A, Rt[0..2], Rf[0..2], 0
#define WS_WEFF 16            // OUTn*Wn = 20152 floats, layout [o][w]

// ---------------- kernel 1: collapsed scalars + effective head matrix ----------------
// Weff[o][w] = sum_c W_lin[o*CW + c*Wn + w] * Wv[c]
// tid = o*Wn + w: consecutive lanes -> consecutive w -> W_lin reads and ws writes coalesced.
__global__ __launch_bounds__(256) void prep_kernel(
    const float* __restrict__ Wq, const float* __restrict__ Wk,
    const float* __restrict__ Wv, const float* __restrict__ rel_t,
    const float* __restrict__ rel_f, const float* __restrict__ W_lin,
    float* __restrict__ ws) {
  __shared__ float wv[Cn];
  if (threadIdx.x < Cn) wv[threadIdx.x] = Wv[threadIdx.x];
  __syncthreads();
  const int tid = blockIdx.x * 256 + threadIdx.x;

  if (tid < 8) {  // block 0 lanes 0..7: the 7 collapsed scalars (+ zero pad)
    float acc = 0.f;
    if (tid == 0) {
      #pragma unroll
      for (int c = 0; c < Cn; ++c) acc += Wq[c] * Wk[c];
    } else if (tid < 4) {
      const int i = tid - 1;
      #pragma unroll
      for (int c = 0; c < 16; ++c) acc += Wq[c] * rel_t[c*3 + i];
    } else if (tid < 7) {
      const int j = tid - 4;
      #pragma unroll
      for (int c = 0; c < 16; ++c) acc += Wq[16 + c] * rel_f[c*3 + j];
    }
    ws[WS_SCAL + tid] = acc;
  }

  if (tid < OUTn * Wn) {
    const int o = tid / Wn;
    const int w = tid - o * Wn;
    const float* src = W_lin + o * CW + w;
    float acc = 0.f;
    #pragma unroll
    for (int c = 0; c < Cn; ++c) acc = fmaf(src[c * Wn], wv[c], acc);
    ws[WS_WEFF + tid] = acc;   // [o][w], coalesced
  }
}

// ---------------- kernel 2: fused attention + head, one block per bh row ----------------
__global__ __launch_bounds__(256) void main_kernel(
    const float* __restrict__ spec, const float* __restrict__ ws,
    const float* __restrict__ b_lin, float* __restrict__ out) {
  __shared__ float srow[3][260];   // 3 spec rows, +1 shift, zero-padded halo
  __shared__ float satt[ATT_ROW + 3];
  __shared__ float sx[232];        // o[w] for this row
  __shared__ float scal[8];

  const int bh = blockIdx.x;       // 0..2047
  const int h  = bh & (Hn - 1);
  const int t  = threadIdx.x;

  if (t < 8) scal[t] = ws[WS_SCAL + t];

  // stage rows h-1, h, h+1 (of the same batch; bh+-1 stays in-batch iff h valid)
  #pragma unroll
  for (int r = 0; r < 3; ++r) {
    const int hh = h + r - 1;
    const bool hin = (unsigned)hh < (unsigned)Hn;
    float v = 0.f;
    if (hin && t < Wn) v = spec[(size_t)(bh + r - 1) * Wn + t];
    srow[r][t + 1] = v;            // t up to 255 -> index up to 256 < 260
    if (t == 255) srow[r][0] = 0.f;
  }
  __syncthreads();

  // per-position attention (threads 0..228)
  if (t < Wn) {
    const int w = t;
    const float A = scal[0];
    const float s = srow[1][w + 1];
    float e[KK], v[KK];
    float m = -1e30f;
    #pragma unroll
    for (int i = 0; i < 3; ++i) {
      const float rt = scal[1 + i];
      #pragma unroll
      for (int j = 0; j < 3; ++j) {
        const int k = i*3 + j;
        const float val = srow[i][w + j];
        v[k] = val;
        const float ek = s * (fmaf(A, val, rt) + scal[4 + j]);
        e[k] = ek;
        m = fmaxf(m, ek);
      }
    }
    float sum = 0.f;
    #pragma unroll
    for (int k = 0; k < KK; ++k) { e[k] = __expf(e[k] - m); sum += e[k]; }
    const float inv = 1.f / sum;
    float o = 0.f;
    #pragma unroll
    for (int k = 0; k < KK; ++k) {
      const float a = e[k] * inv;
      satt[w * KK + k] = a;
      o = fmaf(a, v[k], o);
    }
    sx[w] = o;
  }
  __syncthreads();

  // coalesced attn write: 2061 floats at out[FP_SIZE + bh*2061]
  {
    float* abase = out + FP_SIZE + (size_t)bh * ATT_ROW;
    #pragma unroll
    for (int p = t; p < ATT_ROW; p += 256) abase[p] = satt[p];
  }

  // head: threads 0..87, frame_pred[bh][o] = sigmoid(b[o] + sum_w Weff[o][w]*sx[w])
  if (t < OUTn) {
    const float* wr = ws + WS_WEFF + t * Wn;   // row-contiguous per thread, L2-hot (80 KB total)
    float acc = b_lin[t];
    #pragma unroll 8
    for (int w = 0; w < Wn; ++w) acc = fmaf(wr[w], sx[w], acc);
    out[(size_t)bh * OUTn + t] = 1.f / (1.f + __expf(-acc));
  }
}

extern "C" void kernel_launch(void* const* d_in, const int* in_sizes, int n_in,
                              void* d_out, int out_size, void* d_ws, size_t ws_size,
                              hipStream_t stream) {
  const float* spec  = (const float*)d_in[0];
  const float* Wq    = (const float*)d_in[1];
  const float* Wk    = (const float*)d_in[2];
  const float* Wv    = (const float*)d_in[3];
  const float* rel_t = (const float*)d_in[4];
  const float* rel_f = (const float*)d_in[5];
  const float* W_lin = (const float*)d_in[6];
  const float* b_lin = (const float*)d_in[7];
  float* out = (float*)d_out;
  float* ws  = (float*)d_ws;

  prep_kernel<<<(OUTn*Wn + 255)/256, 256, 0, stream>>>(Wq, Wk, Wv, rel_t, rel_f, W_lin, ws);
  main_kernel<<<BH, 256, 0, stream>>>(spec, ws, b_lin, out);
}